// Round 10
// baseline (110.626 us; speedup 1.0000x reference)
//
#include <hip/hip_runtime.h>
#include <hip/hip_bf16.h>

// ---------------------------------------------------------------------------
// LearnedMeans: 2-NN distances + statistics. R10 = R9 with LDS-traffic cut:
//   dist kernel: block = 128 M x 64 N, 4 waves; wave owns 32 M-rows x 64 cols.
//   - A fragments load DIRECTLY from global (Qb 1MB, L2-hot under XCD remap;
//     1-step register prefetch). A never touches LDS.
//   - B through 8KB single-buffered LDS (R9's verified swizzle/staging).
//   - Per K-step/wave: 8 B ds_reads feed 32 MFMAs (R9: 10 reads / 16 MFMA)
//     -> LDS bytes/FLOP down 2.8x. R9 evidence: 2.35GB LDS traffic ~= 34us
//     floor at 69TB/s = the bound (MfmaUtil 11% invariant to occupancy/L2).
// Fallback to the verified R2 path if ws_size < ~24 MB.
// ---------------------------------------------------------------------------

#define DIM 512
#define M_Q 1024
#define P_TM 4096
#define P_XT 16384
#define P_ALL (P_TM + P_XT)          // 20480
#define NROWS_ALL (M_Q + P_ALL)      // 21504

#define BK 64
#define NSTEP (DIM / BK)             // 8
#define CHUNK 64
#define NCHUNK_TM (P_TM / CHUNK)     // 64
#define NCHUNK_TOT (P_ALL / CHUNK)   // 320
#define BIGF 3.402823466e38f

typedef __bf16 bf16x8 __attribute__((ext_vector_type(8)));
typedef float f32x4 __attribute__((ext_vector_type(4)));
typedef unsigned short u16x8 __attribute__((ext_vector_type(8)));

__device__ __forceinline__ unsigned short f2bf(float f) {
    unsigned int u = __float_as_uint(f);
    unsigned int r = (u + 0x7fffu + ((u >> 16) & 1u)) >> 16;
    return (unsigned short)r;
}

__device__ __forceinline__ void merge1(float v, float& d1, float& d2) {
    if (v < d1) { d2 = d1; d1 = v; }
    else if (v < d2) { d2 = v; }
}

__device__ __forceinline__ void top2_shfl16(float& d1, float& d2) {
    #pragma unroll
    for (int off = 1; off < 16; off <<= 1) {
        float o1 = __shfl_xor(d1, off);
        float o2 = __shfl_xor(d2, off);
        float n1 = fminf(d1, o1);
        float n2 = fminf(fmaxf(d1, o1), fminf(d2, o2));
        d1 = n1; d2 = n2;
    }
}

// ---------------------------------------------------------------------------
// Pass 1: f32 -> bf16 + squared norms. One wave per row (512 elems, 8/lane).
// ---------------------------------------------------------------------------
__global__ __launch_bounds__(256) void convert_norms_kernel(
    const float* __restrict__ Q, const float* __restrict__ TMat,
    const float* __restrict__ XT,
    unsigned short* __restrict__ Qb, unsigned short* __restrict__ Db,
    float* __restrict__ qn, float* __restrict__ dn)
{
    const int wid = threadIdx.x >> 6;
    const int lane = threadIdx.x & 63;
    const int row = blockIdx.x * 4 + wid;

    const float* src;
    unsigned short* dst;
    float* ndst;
    if (row < M_Q) {
        src = Q + (size_t)row * DIM; dst = Qb + (size_t)row * DIM; ndst = qn + row;
    } else {
        int r = row - M_Q;
        src = (row < M_Q + P_TM) ? (TMat + (size_t)r * DIM)
                                 : (XT + (size_t)(row - (M_Q + P_TM)) * DIM);
        dst = Db + (size_t)r * DIM; ndst = dn + r;
    }

    const float* p = src + lane * 8;
    float4 v0 = *(const float4*)p;
    float4 v1 = *(const float4*)(p + 4);
    float s = v0.x*v0.x + v0.y*v0.y + v0.z*v0.z + v0.w*v0.w
            + v1.x*v1.x + v1.y*v1.y + v1.z*v1.z + v1.w*v1.w;

    u16x8 o;
    o[0]=f2bf(v0.x); o[1]=f2bf(v0.y); o[2]=f2bf(v0.z); o[3]=f2bf(v0.w);
    o[4]=f2bf(v1.x); o[5]=f2bf(v1.y); o[6]=f2bf(v1.z); o[7]=f2bf(v1.w);
    *(u16x8*)(dst + lane * 8) = o;

    #pragma unroll
    for (int off = 32; off > 0; off >>= 1) s += __shfl_xor(s, off);
    if (lane == 0) *ndst = s;
}

// ---------------------------------------------------------------------------
// Pass 2: 128x64-tile MFMA distance + per-chunk top-2.
// XCD remap: xcd = bid&7; j = bid>>3; mblk = j&7 (sweep M for fixed B-tile),
//   nchunk = (j>>3)*8 + xcd.  Grid = 2560 blocks.
// Wave wid owns rows [mBase + wid*32, +32) as two 16-row groups g=0,1.
// A: direct global 16B fragment loads (L2-hot), 1-step prefetch.
// B: LDS [64 rows][64 bf16], 16B chunk c of row r at c^(r&7) (R9-verified).
// ---------------------------------------------------------------------------
__global__ __launch_bounds__(256, 5) void dist_mfma_kernel(
    const unsigned short* __restrict__ Qb,   // [M_Q][DIM] bf16
    const unsigned short* __restrict__ Db,   // [P_ALL][DIM] bf16
    const float* __restrict__ qn,            // [M_Q]
    const float* __restrict__ dn,            // [P_ALL]
    float* __restrict__ partial)             // [M_Q][NCHUNK_TOT][2]
{
    __shared__ __align__(16) unsigned short Bs[64 * 64];  // 8 KB

    const int tid  = threadIdx.x;
    const int lane = tid & 63;
    const int wid  = tid >> 6;          // 0..3
    const int r15  = lane & 15;
    const int h    = lane >> 4;         // 0..3

    // --- XCD-aware sweep remap ---
    const int bid    = blockIdx.x;       // 0..2559
    const int xcd    = bid & 7;
    const int j      = bid >> 3;         // 0..319
    const int mblk   = j & 7;            // 8 m-blocks of 128 rows
    const int nchunk = ((j >> 3) << 3) + xcd;   // 0..319
    const int mBase  = mblk * 128;
    const int nBase  = nchunk * 64;

    // --- B staging (verified R9 mapping): thread t -> row t>>2, 2 chunks ---
    const int srow  = tid >> 2;          // 0..63
    const int cpair = (tid & 3) * 2;     // 0,2,4,6
    const unsigned short* gB = Db + (size_t)(nBase + srow) * DIM + cpair * 8;
    const int wB0 = srow * 64 + ((cpair       ^ (srow & 7)) << 3);
    const int wB1 = srow * 64 + (((cpair + 1) ^ (srow & 7)) << 3);

    // --- B ds_read addresses (verified): + nt*1024 per 16-row col group ---
    const int bB0 = r15 * 64 + (((h    ) ^ (r15 & 7)) << 3);
    const int bB1 = r15 * 64 + (((4 | h) ^ (r15 & 7)) << 3);

    // --- A direct-global fragment pointers (per-lane 16B per (g,kh)) ---
    const unsigned short* gA0 = Qb + (size_t)(mBase + wid * 32 + r15) * DIM + h * 8;
    const unsigned short* gA1 = gA0 + (size_t)16 * DIM;

    f32x4 g0n0, g0n1, g0n2, g0n3, g1n0, g1n1, g1n2, g1n3;
    #pragma unroll
    for (int i = 0; i < 4; ++i) {
        g0n0[i]=0.f; g0n1[i]=0.f; g0n2[i]=0.f; g0n3[i]=0.f;
        g1n0[i]=0.f; g1n1[i]=0.f; g1n2[i]=0.f; g1n3[i]=0.f;
    }

    // --- prologue: B stage step 0; A frags for step 0 ---
    u16x8 pb0 = *(const u16x8*)(gB);
    u16x8 pb1 = *(const u16x8*)(gB + 8);
    bf16x8 a00 = *(const bf16x8*)(gA0);          // g0, kh0
    bf16x8 a01 = *(const bf16x8*)(gA0 + 32);     // g0, kh1
    bf16x8 a10 = *(const bf16x8*)(gA1);          // g1, kh0
    bf16x8 a11 = *(const bf16x8*)(gA1 + 32);     // g1, kh1
    *(u16x8*)(&Bs[wB0]) = pb0;
    *(u16x8*)(&Bs[wB1]) = pb1;
    __syncthreads();

    #pragma unroll
    for (int t = 0; t < NSTEP; ++t) {
        bf16x8 n00, n01, n10, n11;
        if (t + 1 < NSTEP) {
            const int ko = (t + 1) * BK;
            pb0 = *(const u16x8*)(gB + ko);
            pb1 = *(const u16x8*)(gB + ko + 8);
            n00 = *(const bf16x8*)(gA0 + ko);
            n01 = *(const bf16x8*)(gA0 + ko + 32);
            n10 = *(const bf16x8*)(gA1 + ko);
            n11 = *(const bf16x8*)(gA1 + ko + 32);
        }

        // kh = 0
        {
            bf16x8 b0 = *(const bf16x8*)(&Bs[bB0]);
            bf16x8 b1 = *(const bf16x8*)(&Bs[bB0 + 1024]);
            bf16x8 b2 = *(const bf16x8*)(&Bs[bB0 + 2048]);
            bf16x8 b3 = *(const bf16x8*)(&Bs[bB0 + 3072]);
            g0n0 = __builtin_amdgcn_mfma_f32_16x16x32_bf16(a00, b0, g0n0, 0, 0, 0);
            g0n1 = __builtin_amdgcn_mfma_f32_16x16x32_bf16(a00, b1, g0n1, 0, 0, 0);
            g0n2 = __builtin_amdgcn_mfma_f32_16x16x32_bf16(a00, b2, g0n2, 0, 0, 0);
            g0n3 = __builtin_amdgcn_mfma_f32_16x16x32_bf16(a00, b3, g0n3, 0, 0, 0);
            g1n0 = __builtin_amdgcn_mfma_f32_16x16x32_bf16(a10, b0, g1n0, 0, 0, 0);
            g1n1 = __builtin_amdgcn_mfma_f32_16x16x32_bf16(a10, b1, g1n1, 0, 0, 0);
            g1n2 = __builtin_amdgcn_mfma_f32_16x16x32_bf16(a10, b2, g1n2, 0, 0, 0);
            g1n3 = __builtin_amdgcn_mfma_f32_16x16x32_bf16(a10, b3, g1n3, 0, 0, 0);
        }
        // kh = 1
        {
            bf16x8 b0 = *(const bf16x8*)(&Bs[bB1]);
            bf16x8 b1 = *(const bf16x8*)(&Bs[bB1 + 1024]);
            bf16x8 b2 = *(const bf16x8*)(&Bs[bB1 + 2048]);
            bf16x8 b3 = *(const bf16x8*)(&Bs[bB1 + 3072]);
            g0n0 = __builtin_amdgcn_mfma_f32_16x16x32_bf16(a01, b0, g0n0, 0, 0, 0);
            g0n1 = __builtin_amdgcn_mfma_f32_16x16x32_bf16(a01, b1, g0n1, 0, 0, 0);
            g0n2 = __builtin_amdgcn_mfma_f32_16x16x32_bf16(a01, b2, g0n2, 0, 0, 0);
            g0n3 = __builtin_amdgcn_mfma_f32_16x16x32_bf16(a01, b3, g0n3, 0, 0, 0);
            g1n0 = __builtin_amdgcn_mfma_f32_16x16x32_bf16(a11, b0, g1n0, 0, 0, 0);
            g1n1 = __builtin_amdgcn_mfma_f32_16x16x32_bf16(a11, b1, g1n1, 0, 0, 0);
            g1n2 = __builtin_amdgcn_mfma_f32_16x16x32_bf16(a11, b2, g1n2, 0, 0, 0);
            g1n3 = __builtin_amdgcn_mfma_f32_16x16x32_bf16(a11, b3, g1n3, 0, 0, 0);
        }

        __syncthreads();                 // done reading Bs for step t

        if (t + 1 < NSTEP) {
            *(u16x8*)(&Bs[wB0]) = pb0;
            *(u16x8*)(&Bs[wB1]) = pb1;
            a00 = n00; a01 = n01; a10 = n10; a11 = n11;
            __syncthreads();             // Bs ready for step t+1
        }
    }

    // --- epilogue x2 groups (R9-verified conventions) ---
    #pragma unroll
    for (int g = 0; g < 2; ++g) {
        const int rbase = mBase + wid * 32 + g * 16 + (h << 2);
        float q2[4];
        #pragma unroll
        for (int r = 0; r < 4; ++r) q2[r] = qn[rbase + r];

        float d1[4], d2[4];
        #pragma unroll
        for (int r = 0; r < 4; ++r) { d1[r] = BIGF; d2[r] = BIGF; }

        #pragma unroll
        for (int nt = 0; nt < 4; ++nt) {
            float dd = dn[nBase + nt * 16 + r15];
            const f32x4& a =
                (g == 0) ? ((nt == 0) ? g0n0 : (nt == 1) ? g0n1 : (nt == 2) ? g0n2 : g0n3)
                         : ((nt == 0) ? g1n0 : (nt == 1) ? g1n1 : (nt == 2) ? g1n2 : g1n3);
            #pragma unroll
            for (int r = 0; r < 4; ++r) {
                float sq = q2[r] + dd - 2.0f * a[r];
                sq = fmaxf(sq, 0.0f);
                merge1(sq, d1[r], d2[r]);
            }
        }

        #pragma unroll
        for (int r = 0; r < 4; ++r) top2_shfl16(d1[r], d2[r]);

        if (r15 == 0) {
            #pragma unroll
            for (int r = 0; r < 4; ++r) {
                size_t base = ((size_t)(rbase + r) * NCHUNK_TOT + nchunk) * 2;
                partial[base]     = d1[r];
                partial[base + 1] = d2[r];
            }
        }
    }
}

// ---------------------------------------------------------------------------
// Pass 3: merge per-chunk top-2 partials (one wave per query).
// ---------------------------------------------------------------------------
__global__ __launch_bounds__(256) void reduce_top2_kernel(
    const float* __restrict__ partial, float* __restrict__ fin)
{
    const int wid  = threadIdx.x >> 6;
    const int lane = threadIdx.x & 63;
    const int m = blockIdx.x * 4 + wid;
    const float* p = partial + (size_t)m * (NCHUNK_TOT * 2);

    float2 v = *(const float2*)(p + 2 * lane);
    float a1 = fminf(v.x, v.y), a2 = fmaxf(v.x, v.y);
    #pragma unroll
    for (int off = 32; off > 0; off >>= 1) {
        float o1 = __shfl_xor(a1, off);
        float o2 = __shfl_xor(a2, off);
        float n1 = fminf(a1, o1);
        float n2 = fminf(fmaxf(a1, o1), fminf(a2, o2));
        a1 = n1; a2 = n2;
    }

    const float* px = p + 2 * NCHUNK_TM + lane * 8;
    float4 w0 = *(const float4*)px;
    float4 w1 = *(const float4*)(px + 4);
    float b1 = BIGF, b2 = BIGF;
    merge1(w0.x, b1, b2); merge1(w0.y, b1, b2);
    merge1(w0.z, b1, b2); merge1(w0.w, b1, b2);
    merge1(w1.x, b1, b2); merge1(w1.y, b1, b2);
    merge1(w1.z, b1, b2); merge1(w1.w, b1, b2);
    #pragma unroll
    for (int off = 32; off > 0; off >>= 1) {
        float o1 = __shfl_xor(b1, off);
        float o2 = __shfl_xor(b2, off);
        float n1 = fminf(b1, o1);
        float n2 = fminf(fmaxf(b1, o1), fminf(b2, o2));
        b1 = n1; b2 = n2;
    }

    if (lane == 0) {
        fin[m]           = sqrtf(a1);
        fin[M_Q + m]     = sqrtf(a2);
        fin[2*M_Q + m]   = sqrtf(b1);
        fin[3*M_Q + m]   = sqrtf(b2);
    }
}

// ---------------------------------------------------------------------------
// Pass 4: stats. Both percentile arrays sorted in ONE bitonic pass.
// ---------------------------------------------------------------------------
__global__ __launch_bounds__(1024) void stats_kernel(
    const float* __restrict__ fin, float* __restrict__ out)
{
    __shared__ float s0[1024];
    __shared__ float s1a[1024];
    __shared__ float red[16][6];
    const int t = threadIdx.x;

    float m1 = fin[t];
    float m2 = fin[1024 + t];
    float s1 = fin[2048 + t];
    float s2 = fin[3072 + t];

    const float T = 1.0f / 3.0f;
    float v[6];
    v[0] = (m1 < T * s1 && m1 < T * m2) ? 1.0f : 0.0f;
    v[1] = (s1 < T * m1 && s1 < T * s2) ? 1.0f : 0.0f;
    v[2] = m1; v[3] = s1; v[4] = m2; v[5] = s2;

    #pragma unroll
    for (int off = 32; off > 0; off >>= 1)
        #pragma unroll
        for (int i = 0; i < 6; ++i) v[i] += __shfl_xor(v[i], off);

    int lane = t & 63, wid = t >> 6;
    if (lane == 0) {
        #pragma unroll
        for (int i = 0; i < 6; ++i) red[wid][i] = v[i];
    }
    __syncthreads();
    if (t == 0) {
        float a[6] = {0, 0, 0, 0, 0, 0};
        for (int w = 0; w < 16; ++w)
            for (int i = 0; i < 6; ++i) a[i] += red[w][i];
        out[0] = a[0];
        out[1] = a[1];
        out[2] = a[2] / 1024.0f;
        out[3] = a[3] / 1024.0f;
        out[4] = a[4] / 1024.0f;
        out[5] = a[5] / 1024.0f;
    }

    s0[t]  = m1;
    s1a[t] = s1;
    __syncthreads();

    for (int k = 2; k <= 1024; k <<= 1) {
        for (int jj = k >> 1; jj > 0; jj >>= 1) {
            int ixj = t ^ jj;
            if (ixj > t) {
                bool up = ((t & k) == 0);
                float a = s0[t], b = s0[ixj];
                if ((a > b) == up) { s0[t] = b; s0[ixj] = a; }
                float c = s1a[t], d = s1a[ixj];
                if ((c > d) == up) { s1a[t] = d; s1a[ixj] = c; }
            }
            __syncthreads();
        }
    }

    if (t < 5) {
        const float P[5] = {10.f, 25.f, 50.f, 75.f, 90.f};
        float q = P[t] * 1023.0f / 100.0f;
        int lo = (int)q;
        float fr = q - (float)lo;
        out[6 + t]  = s0[lo]  + fr * (s0[lo + 1]  - s0[lo]);
        out[11 + t] = s1a[lo] + fr * (s1a[lo + 1] - s1a[lo]);
    }
}

// ---------------------------------------------------------------------------
// Fallback path (verified R2 kernels) — used only if ws_size is too small.
// ---------------------------------------------------------------------------
__global__ __launch_bounds__(256) void norms_kernel_fb(
    const float* __restrict__ src, float* __restrict__ dst, int nrows)
{
    int wid = threadIdx.x >> 6;
    int lane = threadIdx.x & 63;
    int row = blockIdx.x * 4 + wid;
    if (row >= nrows) return;
    const float* p = src + (size_t)row * DIM + lane * 8;
    float4 v0 = *(const float4*)p;
    float4 v1 = *(const float4*)(p + 4);
    float s = v0.x*v0.x + v0.y*v0.y + v0.z*v0.z + v0.w*v0.w
            + v1.x*v1.x + v1.y*v1.y + v1.z*v1.z + v1.w*v1.w;
    #pragma unroll
    for (int off = 32; off > 0; off >>= 1) s += __shfl_xor(s, off);
    if (lane == 0) dst[row] = s;
}

__global__ __launch_bounds__(256) void dist_top2_kernel_fb(
    const float* __restrict__ Q, const float* __restrict__ Dset,
    const float* __restrict__ qn, const float* __restrict__ dn,
    float* __restrict__ partial, int chunkGlobalOffset)
{
    __shared__ __align__(16) unsigned short As[64][40];
    __shared__ __align__(16) unsigned short Bs[64][40];

    const int tid  = threadIdx.x;
    const int lane = tid & 63;
    const int wid  = tid >> 6;
    const int mBase = blockIdx.y * 64;
    const int nBase = blockIdx.x * 64;

    const int srow = tid >> 2;
    const int skc  = (tid & 3) * 8;

    const float* qrow = Q    + (size_t)(mBase + srow) * DIM + skc;
    const float* drow = Dset + (size_t)(nBase + srow) * DIM + skc;

    f32x4 acc[4];
    #pragma unroll
    for (int nt = 0; nt < 4; ++nt)
        #pragma unroll
        for (int i = 0; i < 4; ++i) acc[nt][i] = 0.0f;

    const int frow = lane & 15;
    const int fk   = (lane >> 4) * 8;

    for (int ks = 0; ks < DIM; ks += 32) {
        float4 a0 = *(const float4*)(qrow + ks);
        float4 a1 = *(const float4*)(qrow + ks + 4);
        float4 b0 = *(const float4*)(drow + ks);
        float4 b1 = *(const float4*)(drow + ks + 4);

        u16x8 va, vb;
        va[0]=f2bf(a0.x); va[1]=f2bf(a0.y); va[2]=f2bf(a0.z); va[3]=f2bf(a0.w);
        va[4]=f2bf(a1.x); va[5]=f2bf(a1.y); va[6]=f2bf(a1.z); va[7]=f2bf(a1.w);
        vb[0]=f2bf(b0.x); vb[1]=f2bf(b0.y); vb[2]=f2bf(b0.z); vb[3]=f2bf(b0.w);
        vb[4]=f2bf(b1.x); vb[5]=f2bf(b1.y); vb[6]=f2bf(b1.z); vb[7]=f2bf(b1.w);

        *(u16x8*)(&As[srow][skc]) = va;
        *(u16x8*)(&Bs[srow][skc]) = vb;
        __syncthreads();

        bf16x8 af = *(const bf16x8*)(&As[wid * 16 + frow][fk]);
        #pragma unroll
        for (int nt = 0; nt < 4; ++nt) {
            bf16x8 bf = *(const bf16x8*)(&Bs[nt * 16 + frow][fk]);
            acc[nt] = __builtin_amdgcn_mfma_f32_16x16x32_bf16(af, bf, acc[nt], 0, 0, 0);
        }
        __syncthreads();
    }

    const int rbase = mBase + wid * 16 + ((lane >> 4) << 2);
    float q2[4];
    #pragma unroll
    for (int r = 0; r < 4; ++r) q2[r] = qn[rbase + r];

    float d1[4], d2[4];
    #pragma unroll
    for (int r = 0; r < 4; ++r) { d1[r] = BIGF; d2[r] = BIGF; }

    #pragma unroll
    for (int nt = 0; nt < 4; ++nt) {
        float dd = dn[nBase + nt * 16 + (lane & 15)];
        #pragma unroll
        for (int r = 0; r < 4; ++r) {
            float sq = q2[r] + dd - 2.0f * acc[nt][r];
            sq = fmaxf(sq, 0.0f);
            merge1(sq, d1[r], d2[r]);
        }
    }

    #pragma unroll
    for (int r = 0; r < 4; ++r) top2_shfl16(d1[r], d2[r]);

    if ((lane & 15) == 0) {
        int chunkG = chunkGlobalOffset + blockIdx.x;
        #pragma unroll
        for (int r = 0; r < 4; ++r) {
            size_t base = ((size_t)(rbase + r) * NCHUNK_TOT + chunkG) * 2;
            partial[base]     = d1[r];
            partial[base + 1] = d2[r];
        }
    }
}

// ---------------------------------------------------------------------------
extern "C" void kernel_launch(void* const* d_in, const int* in_sizes, int n_in,
                              void* d_out, int out_size, void* d_ws, size_t ws_size,
                              hipStream_t stream) {
    const float* Q  = (const float*)d_in[0];
    const float* TM = (const float*)d_in[1];
    const float* XT = (const float*)d_in[2];
    float* out = (float*)d_out;

    const size_t needMain =
        (size_t)M_Q * DIM * 2 + (size_t)P_ALL * DIM * 2 +
        4 * ((size_t)M_Q + P_ALL + (size_t)M_Q * NCHUNK_TOT * 2 + 4 * M_Q);

    if (ws_size >= needMain) {
        char* w = (char*)d_ws;
        unsigned short* Qb = (unsigned short*)w;
        unsigned short* Db = (unsigned short*)(w + (size_t)M_Q * DIM * 2);
        float* qn = (float*)(w + (size_t)M_Q * DIM * 2 + (size_t)P_ALL * DIM * 2);
        float* dn = qn + M_Q;
        float* partial = dn + P_ALL;
        float* fin = partial + (size_t)M_Q * NCHUNK_TOT * 2;

        convert_norms_kernel<<<dim3(NROWS_ALL / 4), 256, 0, stream>>>(
            Q, TM, XT, Qb, Db, qn, dn);
        dist_mfma_kernel<<<dim3(NCHUNK_TOT * (M_Q / 128)), 256, 0, stream>>>(
            Qb, Db, qn, dn, partial);
        reduce_top2_kernel<<<dim3(M_Q / 4), 256, 0, stream>>>(partial, fin);
        stats_kernel<<<dim3(1), 1024, 0, stream>>>(fin, out);
    } else {
        float* ws = (float*)d_ws;
        float* qn = ws;
        float* dn = ws + M_Q;
        float* partial = dn + P_ALL;
        float* fin = partial + (size_t)M_Q * NCHUNK_TOT * 2;

        norms_kernel_fb<<<dim3(M_Q / 4),  256, 0, stream>>>(Q,  qn, M_Q);
        norms_kernel_fb<<<dim3(P_TM / 4), 256, 0, stream>>>(TM, dn, P_TM);
        norms_kernel_fb<<<dim3(P_XT / 4), 256, 0, stream>>>(XT, dn + P_TM, P_XT);
        dist_top2_kernel_fb<<<dim3(P_TM / 64, M_Q / 64), 256, 0, stream>>>(
            Q, TM, qn, dn, partial, 0);
        dist_top2_kernel_fb<<<dim3(P_XT / 64, M_Q / 64), 256, 0, stream>>>(
            Q, XT, qn, dn + P_TM, partial, NCHUNK_TM);
        reduce_top2_kernel<<<dim3(M_Q / 4), 256, 0, stream>>>(partial, fin);
        stats_kernel<<<dim3(1), 1024, 0, stream>>>(fin, out);
    }
}

// Round 11
// 107.702 us; speedup vs baseline: 1.0271x; 1.0271x over previous
//
#include <hip/hip_runtime.h>
#include <hip/hip_bf16.h>

// ---------------------------------------------------------------------------
// LearnedMeans: 2-NN distances + statistics. R11 = R9 structure with
// sink-proof staging (the one lever not yet isolated):
//   dist kernel: 64x64 tile, 4 waves, BK=64, DOUBLE-buffered 2x16KB LDS,
//   staging via global_load_lds w=16 (fire-and-forget: no dest register, so
//   the compiler CANNOT sink the issue to the use point -- R8/R9/R10's
//   reg-prefetch was provably sunk: VGPR_Count 32-44 can't hold the prefetch
//   state, and time was invariant to occupancy/L2/LDS fixes = exposed
//   latency). One barrier per K-step: STAGE(buf^1) -> compute(buf) -> barrier
//   (T3-minimum). Swizzle identical to R9 reads; gload_lds inverse-swizzled
//   per-lane SOURCE + linear wave-uniform dest (verified correct in R3/R4).
//   XCD remap kept (FETCH 88->31MB, verified).
// Fallback to the verified R2 path if ws_size < ~24 MB.
// ---------------------------------------------------------------------------

#define DIM 512
#define M_Q 1024
#define P_TM 4096
#define P_XT 16384
#define P_ALL (P_TM + P_XT)          // 20480
#define NROWS_ALL (M_Q + P_ALL)      // 21504

#define BK 64
#define NSTEP (DIM / BK)             // 8
#define CHUNK 64
#define NCHUNK_TM (P_TM / CHUNK)     // 64
#define NCHUNK_TOT (P_ALL / CHUNK)   // 320
#define BIGF 3.402823466e38f

typedef __bf16 bf16x8 __attribute__((ext_vector_type(8)));
typedef float f32x4 __attribute__((ext_vector_type(4)));
typedef unsigned short u16x8 __attribute__((ext_vector_type(8)));

__device__ __forceinline__ unsigned short f2bf(float f) {
    unsigned int u = __float_as_uint(f);
    unsigned int r = (u + 0x7fffu + ((u >> 16) & 1u)) >> 16;
    return (unsigned short)r;
}

__device__ __forceinline__ void merge1(float v, float& d1, float& d2) {
    if (v < d1) { d2 = d1; d1 = v; }
    else if (v < d2) { d2 = v; }
}

__device__ __forceinline__ void top2_shfl16(float& d1, float& d2) {
    #pragma unroll
    for (int off = 1; off < 16; off <<= 1) {
        float o1 = __shfl_xor(d1, off);
        float o2 = __shfl_xor(d2, off);
        float n1 = fminf(d1, o1);
        float n2 = fminf(fmaxf(d1, o1), fminf(d2, o2));
        d1 = n1; d2 = n2;
    }
}

__device__ __forceinline__ void async_copy16(const void* g, void* l) {
    __builtin_amdgcn_global_load_lds(
        (const __attribute__((address_space(1))) void*)g,
        (__attribute__((address_space(3))) void*)l,
        16, 0, 0);
}

// ---------------------------------------------------------------------------
// Pass 1: f32 -> bf16 + squared norms. One wave per row (512 elems, 8/lane).
// ---------------------------------------------------------------------------
__global__ __launch_bounds__(256) void convert_norms_kernel(
    const float* __restrict__ Q, const float* __restrict__ TMat,
    const float* __restrict__ XT,
    unsigned short* __restrict__ Qb, unsigned short* __restrict__ Db,
    float* __restrict__ qn, float* __restrict__ dn)
{
    const int wid = threadIdx.x >> 6;
    const int lane = threadIdx.x & 63;
    const int row = blockIdx.x * 4 + wid;

    const float* src;
    unsigned short* dst;
    float* ndst;
    if (row < M_Q) {
        src = Q + (size_t)row * DIM; dst = Qb + (size_t)row * DIM; ndst = qn + row;
    } else {
        int r = row - M_Q;
        src = (row < M_Q + P_TM) ? (TMat + (size_t)r * DIM)
                                 : (XT + (size_t)(row - (M_Q + P_TM)) * DIM);
        dst = Db + (size_t)r * DIM; ndst = dn + r;
    }

    const float* p = src + lane * 8;
    float4 v0 = *(const float4*)p;
    float4 v1 = *(const float4*)(p + 4);
    float s = v0.x*v0.x + v0.y*v0.y + v0.z*v0.z + v0.w*v0.w
            + v1.x*v1.x + v1.y*v1.y + v1.z*v1.z + v1.w*v1.w;

    u16x8 o;
    o[0]=f2bf(v0.x); o[1]=f2bf(v0.y); o[2]=f2bf(v0.z); o[3]=f2bf(v0.w);
    o[4]=f2bf(v1.x); o[5]=f2bf(v1.y); o[6]=f2bf(v1.z); o[7]=f2bf(v1.w);
    *(u16x8*)(dst + lane * 8) = o;

    #pragma unroll
    for (int off = 32; off > 0; off >>= 1) s += __shfl_xor(s, off);
    if (lane == 0) *ndst = s;
}

// ---------------------------------------------------------------------------
// Pass 2: 64x64-tile MFMA distance + per-chunk top-2, double-buffered
// global_load_lds staging (sink-proof), one barrier per K-step.
//
// LDS logical layout per buffer: [64 rows][64 bf16] (128B row = 8x16B chunks);
// logical chunk c of row r stored at physical chunk c^(r&7).
// gload_lds slab s = i*4+wid (i=0,1) covers rows [s*8, s*8+8): lane writes
// phys byte s*1024 + lane*16 -> row = s*8 + (lane>>3), cphys = lane&7,
// source logical chunk clog = (lane&7) ^ ((lane>>3)&7)  [since row&7=lane>>3].
// ds_read addrs identical to R8/R9 (verified).
// ---------------------------------------------------------------------------
__global__ __launch_bounds__(256, 5) void dist_mfma_kernel(
    const unsigned short* __restrict__ Qb,   // [M_Q][DIM] bf16
    const unsigned short* __restrict__ Db,   // [P_ALL][DIM] bf16
    const float* __restrict__ qn,            // [M_Q]
    const float* __restrict__ dn,            // [P_ALL]
    float* __restrict__ partial)             // [M_Q][NCHUNK_TOT][2]
{
    __shared__ __align__(16) unsigned short As[2][64 * 64];  // 2 x 8 KB
    __shared__ __align__(16) unsigned short Bs[2][64 * 64];  // 2 x 8 KB

    const int tid  = threadIdx.x;
    const int lane = tid & 63;
    const int wid  = tid >> 6;          // 0..3
    const int r15  = lane & 15;
    const int h    = lane >> 4;         // 0..3

    // --- XCD-aware sweep remap (verified R9) ---
    const int bid    = blockIdx.x;       // 0..5119
    const int xcd    = bid & 7;
    const int j      = bid >> 3;         // 0..639
    const int mblk   = j & 15;
    const int nchunk = ((j >> 4) << 3) + xcd;   // 0..319
    const int mBase  = mblk * 64;
    const int nBase  = nchunk * 64;

    // --- gload_lds staging: slabs s0 = wid, s1 = 4+wid (1 KB each) ---
    const int rowS0 = wid * 8 + (lane >> 3);          // rows 0..31
    const int clog  = (lane & 7) ^ ((lane >> 3) & 7); // inverse swizzle
    const unsigned short* srcA0 = Qb + (size_t)(mBase + rowS0) * DIM + clog * 8;
    const unsigned short* srcA1 = srcA0 + (size_t)32 * DIM;   // rows 32..63
    const unsigned short* srcB0 = Db + (size_t)(nBase + rowS0) * DIM + clog * 8;
    const unsigned short* srcB1 = srcB0 + (size_t)32 * DIM;
    const int ldsOff0 = wid * 1024;         // byte offset, wave-uniform
    const int ldsOff1 = (4 + wid) * 1024;

    // --- ds_read addresses (ushort idx; verified R8/R9) ---
    const int aA0 = (wid * 16 + r15) * 64 + (((h    ) ^ (r15 & 7)) << 3);
    const int aA1 = (wid * 16 + r15) * 64 + (((4 | h) ^ (r15 & 7)) << 3);
    const int bB0 = r15 * 64 + (((h    ) ^ (r15 & 7)) << 3);
    const int bB1 = r15 * 64 + (((4 | h) ^ (r15 & 7)) << 3);

    f32x4 acc0, acc1, acc2, acc3;
    #pragma unroll
    for (int i = 0; i < 4; ++i) { acc0[i]=0.f; acc1[i]=0.f; acc2[i]=0.f; acc3[i]=0.f; }

    // --- prologue: stage K-step 0 into buffer 0 ---
    async_copy16(srcA0, (char*)&As[0][0] + ldsOff0);
    async_copy16(srcA1, (char*)&As[0][0] + ldsOff1);
    async_copy16(srcB0, (char*)&Bs[0][0] + ldsOff0);
    async_copy16(srcB1, (char*)&Bs[0][0] + ldsOff1);
    __syncthreads();   // vmcnt(0) drain: buf0 resident

    #pragma unroll
    for (int t = 0; t < NSTEP; ++t) {
        const int cur = t & 1;

        // issue next-step staging FIRST (fire-and-forget: cannot be sunk)
        if (t + 1 < NSTEP) {
            const int ks = (t + 1) * BK;
            async_copy16(srcA0 + ks, (char*)&As[cur ^ 1][0] + ldsOff0);
            async_copy16(srcA1 + ks, (char*)&As[cur ^ 1][0] + ldsOff1);
            async_copy16(srcB0 + ks, (char*)&Bs[cur ^ 1][0] + ldsOff0);
            async_copy16(srcB1 + ks, (char*)&Bs[cur ^ 1][0] + ldsOff1);
        }

        // compute step t from buf cur (loads for t+1 in flight underneath)
        // kh = 0
        {
            bf16x8 af = *(const bf16x8*)(&As[cur][aA0]);
            bf16x8 b0 = *(const bf16x8*)(&Bs[cur][bB0]);
            bf16x8 b1 = *(const bf16x8*)(&Bs[cur][bB0 + 1024]);
            bf16x8 b2 = *(const bf16x8*)(&Bs[cur][bB0 + 2048]);
            bf16x8 b3 = *(const bf16x8*)(&Bs[cur][bB0 + 3072]);
            acc0 = __builtin_amdgcn_mfma_f32_16x16x32_bf16(af, b0, acc0, 0, 0, 0);
            acc1 = __builtin_amdgcn_mfma_f32_16x16x32_bf16(af, b1, acc1, 0, 0, 0);
            acc2 = __builtin_amdgcn_mfma_f32_16x16x32_bf16(af, b2, acc2, 0, 0, 0);
            acc3 = __builtin_amdgcn_mfma_f32_16x16x32_bf16(af, b3, acc3, 0, 0, 0);
        }
        // kh = 1
        {
            bf16x8 af = *(const bf16x8*)(&As[cur][aA1]);
            bf16x8 b0 = *(const bf16x8*)(&Bs[cur][bB1]);
            bf16x8 b1 = *(const bf16x8*)(&Bs[cur][bB1 + 1024]);
            bf16x8 b2 = *(const bf16x8*)(&Bs[cur][bB1 + 2048]);
            bf16x8 b3 = *(const bf16x8*)(&Bs[cur][bB1 + 3072]);
            acc0 = __builtin_amdgcn_mfma_f32_16x16x32_bf16(af, b0, acc0, 0, 0, 0);
            acc1 = __builtin_amdgcn_mfma_f32_16x16x32_bf16(af, b1, acc1, 0, 0, 0);
            acc2 = __builtin_amdgcn_mfma_f32_16x16x32_bf16(af, b2, acc2, 0, 0, 0);
            acc3 = __builtin_amdgcn_mfma_f32_16x16x32_bf16(af, b3, acc3, 0, 0, 0);
        }

        // ONE barrier per step: vmcnt(0)+lgkmcnt(0) drain => staged t+1
        // landed (had full compute phase to arrive) AND all waves done
        // reading buf cur before next iteration stages into it.
        __syncthreads();
    }

    // --- epilogue (verified conventions): row=rbase+r, col=nBase+nt*16+r15 ---
    const int rbase = mBase + wid * 16 + (h << 2);
    float q2[4];
    #pragma unroll
    for (int r = 0; r < 4; ++r) q2[r] = qn[rbase + r];

    float d1[4], d2[4];
    #pragma unroll
    for (int r = 0; r < 4; ++r) { d1[r] = BIGF; d2[r] = BIGF; }

    #pragma unroll
    for (int nt = 0; nt < 4; ++nt) {
        float dd = dn[nBase + nt * 16 + r15];
        const f32x4& a = (nt == 0) ? acc0 : (nt == 1) ? acc1 : (nt == 2) ? acc2 : acc3;
        #pragma unroll
        for (int r = 0; r < 4; ++r) {
            float sq = q2[r] + dd - 2.0f * a[r];
            sq = fmaxf(sq, 0.0f);
            merge1(sq, d1[r], d2[r]);
        }
    }

    #pragma unroll
    for (int r = 0; r < 4; ++r) top2_shfl16(d1[r], d2[r]);

    if (r15 == 0) {
        #pragma unroll
        for (int r = 0; r < 4; ++r) {
            size_t base = ((size_t)(rbase + r) * NCHUNK_TOT + nchunk) * 2;
            partial[base]     = d1[r];
            partial[base + 1] = d2[r];
        }
    }
}

// ---------------------------------------------------------------------------
// Pass 3: merge per-chunk top-2 partials (one wave per query).
// ---------------------------------------------------------------------------
__global__ __launch_bounds__(256) void reduce_top2_kernel(
    const float* __restrict__ partial, float* __restrict__ fin)
{
    const int wid  = threadIdx.x >> 6;
    const int lane = threadIdx.x & 63;
    const int m = blockIdx.x * 4 + wid;
    const float* p = partial + (size_t)m * (NCHUNK_TOT * 2);

    float2 v = *(const float2*)(p + 2 * lane);
    float a1 = fminf(v.x, v.y), a2 = fmaxf(v.x, v.y);
    #pragma unroll
    for (int off = 32; off > 0; off >>= 1) {
        float o1 = __shfl_xor(a1, off);
        float o2 = __shfl_xor(a2, off);
        float n1 = fminf(a1, o1);
        float n2 = fminf(fmaxf(a1, o1), fminf(a2, o2));
        a1 = n1; a2 = n2;
    }

    const float* px = p + 2 * NCHUNK_TM + lane * 8;
    float4 w0 = *(const float4*)px;
    float4 w1 = *(const float4*)(px + 4);
    float b1 = BIGF, b2 = BIGF;
    merge1(w0.x, b1, b2); merge1(w0.y, b1, b2);
    merge1(w0.z, b1, b2); merge1(w0.w, b1, b2);
    merge1(w1.x, b1, b2); merge1(w1.y, b1, b2);
    merge1(w1.z, b1, b2); merge1(w1.w, b1, b2);
    #pragma unroll
    for (int off = 32; off > 0; off >>= 1) {
        float o1 = __shfl_xor(b1, off);
        float o2 = __shfl_xor(b2, off);
        float n1 = fminf(b1, o1);
        float n2 = fminf(fmaxf(b1, o1), fminf(b2, o2));
        b1 = n1; b2 = n2;
    }

    if (lane == 0) {
        fin[m]           = sqrtf(a1);
        fin[M_Q + m]     = sqrtf(a2);
        fin[2*M_Q + m]   = sqrtf(b1);
        fin[3*M_Q + m]   = sqrtf(b2);
    }
}

// ---------------------------------------------------------------------------
// Pass 4: stats. Both percentile arrays sorted in ONE bitonic pass.
// ---------------------------------------------------------------------------
__global__ __launch_bounds__(1024) void stats_kernel(
    const float* __restrict__ fin, float* __restrict__ out)
{
    __shared__ float s0[1024];
    __shared__ float s1a[1024];
    __shared__ float red[16][6];
    const int t = threadIdx.x;

    float m1 = fin[t];
    float m2 = fin[1024 + t];
    float s1 = fin[2048 + t];
    float s2 = fin[3072 + t];

    const float T = 1.0f / 3.0f;
    float v[6];
    v[0] = (m1 < T * s1 && m1 < T * m2) ? 1.0f : 0.0f;
    v[1] = (s1 < T * m1 && s1 < T * s2) ? 1.0f : 0.0f;
    v[2] = m1; v[3] = s1; v[4] = m2; v[5] = s2;

    #pragma unroll
    for (int off = 32; off > 0; off >>= 1)
        #pragma unroll
        for (int i = 0; i < 6; ++i) v[i] += __shfl_xor(v[i], off);

    int lane = t & 63, wid = t >> 6;
    if (lane == 0) {
        #pragma unroll
        for (int i = 0; i < 6; ++i) red[wid][i] = v[i];
    }
    __syncthreads();
    if (t == 0) {
        float a[6] = {0, 0, 0, 0, 0, 0};
        for (int w = 0; w < 16; ++w)
            for (int i = 0; i < 6; ++i) a[i] += red[w][i];
        out[0] = a[0];
        out[1] = a[1];
        out[2] = a[2] / 1024.0f;
        out[3] = a[3] / 1024.0f;
        out[4] = a[4] / 1024.0f;
        out[5] = a[5] / 1024.0f;
    }

    s0[t]  = m1;
    s1a[t] = s1;
    __syncthreads();

    for (int k = 2; k <= 1024; k <<= 1) {
        for (int jj = k >> 1; jj > 0; jj >>= 1) {
            int ixj = t ^ jj;
            if (ixj > t) {
                bool up = ((t & k) == 0);
                float a = s0[t], b = s0[ixj];
                if ((a > b) == up) { s0[t] = b; s0[ixj] = a; }
                float c = s1a[t], d = s1a[ixj];
                if ((c > d) == up) { s1a[t] = d; s1a[ixj] = c; }
            }
            __syncthreads();
        }
    }

    if (t < 5) {
        const float P[5] = {10.f, 25.f, 50.f, 75.f, 90.f};
        float q = P[t] * 1023.0f / 100.0f;
        int lo = (int)q;
        float fr = q - (float)lo;
        out[6 + t]  = s0[lo]  + fr * (s0[lo + 1]  - s0[lo]);
        out[11 + t] = s1a[lo] + fr * (s1a[lo + 1] - s1a[lo]);
    }
}

// ---------------------------------------------------------------------------
// Fallback path (verified R2 kernels) — used only if ws_size is too small.
// ---------------------------------------------------------------------------
__global__ __launch_bounds__(256) void norms_kernel_fb(
    const float* __restrict__ src, float* __restrict__ dst, int nrows)
{
    int wid = threadIdx.x >> 6;
    int lane = threadIdx.x & 63;
    int row = blockIdx.x * 4 + wid;
    if (row >= nrows) return;
    const float* p = src + (size_t)row * DIM + lane * 8;
    float4 v0 = *(const float4*)p;
    float4 v1 = *(const float4*)(p + 4);
    float s = v0.x*v0.x + v0.y*v0.y + v0.z*v0.z + v0.w*v0.w
            + v1.x*v1.x + v1.y*v1.y + v1.z*v1.z + v1.w*v1.w;
    #pragma unroll
    for (int off = 32; off > 0; off >>= 1) s += __shfl_xor(s, off);
    if (lane == 0) dst[row] = s;
}

__global__ __launch_bounds__(256) void dist_top2_kernel_fb(
    const float* __restrict__ Q, const float* __restrict__ Dset,
    const float* __restrict__ qn, const float* __restrict__ dn,
    float* __restrict__ partial, int chunkGlobalOffset)
{
    __shared__ __align__(16) unsigned short As[64][40];
    __shared__ __align__(16) unsigned short Bs[64][40];

    const int tid  = threadIdx.x;
    const int lane = tid & 63;
    const int wid  = tid >> 6;
    const int mBase = blockIdx.y * 64;
    const int nBase = blockIdx.x * 64;

    const int srow = tid >> 2;
    const int skc  = (tid & 3) * 8;

    const float* qrow = Q    + (size_t)(mBase + srow) * DIM + skc;
    const float* drow = Dset + (size_t)(nBase + srow) * DIM + skc;

    f32x4 acc[4];
    #pragma unroll
    for (int nt = 0; nt < 4; ++nt)
        #pragma unroll
        for (int i = 0; i < 4; ++i) acc[nt][i] = 0.0f;

    const int frow = lane & 15;
    const int fk   = (lane >> 4) * 8;

    for (int ks = 0; ks < DIM; ks += 32) {
        float4 a0 = *(const float4*)(qrow + ks);
        float4 a1 = *(const float4*)(qrow + ks + 4);
        float4 b0 = *(const float4*)(drow + ks);
        float4 b1 = *(const float4*)(drow + ks + 4);

        u16x8 va, vb;
        va[0]=f2bf(a0.x); va[1]=f2bf(a0.y); va[2]=f2bf(a0.z); va[3]=f2bf(a0.w);
        va[4]=f2bf(a1.x); va[5]=f2bf(a1.y); va[6]=f2bf(a1.z); va[7]=f2bf(a1.w);
        vb[0]=f2bf(b0.x); vb[1]=f2bf(b0.y); vb[2]=f2bf(b0.z); vb[3]=f2bf(b0.w);
        vb[4]=f2bf(b1.x); vb[5]=f2bf(b1.y); vb[6]=f2bf(b1.z); vb[7]=f2bf(b1.w);

        *(u16x8*)(&As[srow][skc]) = va;
        *(u16x8*)(&Bs[srow][skc]) = vb;
        __syncthreads();

        bf16x8 af = *(const bf16x8*)(&As[wid * 16 + frow][fk]);
        #pragma unroll
        for (int nt = 0; nt < 4; ++nt) {
            bf16x8 bf = *(const bf16x8*)(&Bs[nt * 16 + frow][fk]);
            acc[nt] = __builtin_amdgcn_mfma_f32_16x16x32_bf16(af, bf, acc[nt], 0, 0, 0);
        }
        __syncthreads();
    }

    const int rbase = mBase + wid * 16 + ((lane >> 4) << 2);
    float q2[4];
    #pragma unroll
    for (int r = 0; r < 4; ++r) q2[r] = qn[rbase + r];

    float d1[4], d2[4];
    #pragma unroll
    for (int r = 0; r < 4; ++r) { d1[r] = BIGF; d2[r] = BIGF; }

    #pragma unroll
    for (int nt = 0; nt < 4; ++nt) {
        float dd = dn[nBase + nt * 16 + (lane & 15)];
        #pragma unroll
        for (int r = 0; r < 4; ++r) {
            float sq = q2[r] + dd - 2.0f * acc[nt][r];
            sq = fmaxf(sq, 0.0f);
            merge1(sq, d1[r], d2[r]);
        }
    }

    #pragma unroll
    for (int r = 0; r < 4; ++r) top2_shfl16(d1[r], d2[r]);

    if ((lane & 15) == 0) {
        int chunkG = chunkGlobalOffset + blockIdx.x;
        #pragma unroll
        for (int r = 0; r < 4; ++r) {
            size_t base = ((size_t)(rbase + r) * NCHUNK_TOT + chunkG) * 2;
            partial[base]     = d1[r];
            partial[base + 1] = d2[r];
        }
    }
}

// ---------------------------------------------------------------------------
extern "C" void kernel_launch(void* const* d_in, const int* in_sizes, int n_in,
                              void* d_out, int out_size, void* d_ws, size_t ws_size,
                              hipStream_t stream) {
    const float* Q  = (const float*)d_in[0];
    const float* TM = (const float*)d_in[1];
    const float* XT = (const float*)d_in[2];
    float* out = (float*)d_out;

    const size_t needMain =
        (size_t)M_Q * DIM * 2 + (size_t)P_ALL * DIM * 2 +
        4 * ((size_t)M_Q + P_ALL + (size_t)M_Q * NCHUNK_TOT * 2 + 4 * M_Q);

    if (ws_size >= needMain) {
        char* w = (char*)d_ws;
        unsigned short* Qb = (unsigned short*)w;
        unsigned short* Db = (unsigned short*)(w + (size_t)M_Q * DIM * 2);
        float* qn = (float*)(w + (size_t)M_Q * DIM * 2 + (size_t)P_ALL * DIM * 2);
        float* dn = qn + M_Q;
        float* partial = dn + P_ALL;
        float* fin = partial + (size_t)M_Q * NCHUNK_TOT * 2;

        convert_norms_kernel<<<dim3(NROWS_ALL / 4), 256, 0, stream>>>(
            Q, TM, XT, Qb, Db, qn, dn);
        dist_mfma_kernel<<<dim3(NCHUNK_TOT * (M_Q / 64)), 256, 0, stream>>>(
            Qb, Db, qn, dn, partial);
        reduce_top2_kernel<<<dim3(M_Q / 4), 256, 0, stream>>>(partial, fin);
        stats_kernel<<<dim3(1), 1024, 0, stream>>>(fin, out);
    } else {
        float* ws = (float*)d_ws;
        float* qn = ws;
        float* dn = ws + M_Q;
        float* partial = dn + P_ALL;
        float* fin = partial + (size_t)M_Q * NCHUNK_TOT * 2;

        norms_kernel_fb<<<dim3(M_Q / 4),  256, 0, stream>>>(Q,  qn, M_Q);
        norms_kernel_fb<<<dim3(P_TM / 4), 256, 0, stream>>>(TM, dn, P_TM);
        norms_kernel_fb<<<dim3(P_XT / 4), 256, 0, stream>>>(XT, dn + P_TM, P_XT);
        dist_top2_kernel_fb<<<dim3(P_TM / 64, M_Q / 64), 256, 0, stream>>>(
            Q, TM, qn, dn, partial, 0);
        dist_top2_kernel_fb<<<dim3(P_XT / 64, M_Q / 64), 256, 0, stream>>>(
            Q, XT, qn, dn + P_TM, partial, NCHUNK_TM);
        reduce_top2_kernel<<<dim3(M_Q / 4), 256, 0, stream>>>(partial, fin);
        stats_kernel<<<dim3(1), 1024, 0, stream>>>(fin, out);
    }
}